// Round 1
// baseline (264.374 us; speedup 1.0000x reference)
//
#include <hip/hip_runtime.h>

#define OUT 7
#define NB 4        // batch
#define NC 256      // channels
#define NN 256      // rois per image
#define ELEMS_PER_ROI (NC * OUT * OUT)   // 12544

__global__ __launch_bounds__(256) void msroi_kernel(
    const float* __restrict__ f0, const float* __restrict__ f1,
    const float* __restrict__ f2, const float* __restrict__ f3,
    const float* __restrict__ f4, const float* __restrict__ rois,
    float* __restrict__ out)
{
    const int roi = blockIdx.y;
    const int tid = threadIdx.x;

    __shared__ float s_ly[14], s_lx[14];
    __shared__ int   s_y0[14], s_y1[14], s_x0[14], s_x1[14];
    __shared__ int   s_yv[14], s_xv[14];
    __shared__ int   s_lvl;

    if (tid < 28) {
        const float rx1 = rois[roi * 4 + 0];
        const float ry1 = rois[roi * 4 + 1];
        const float rx2 = rois[roi * 4 + 2];
        const float ry2 = rois[roi * 4 + 3];

        float area = (rx2 - rx1) * (ry2 - ry1);
        float lf = floorf(4.0f + log2f(sqrtf(area) / 224.0f + 1e-6f));
        lf = fminf(fmaxf(lf, 2.0f), 6.0f);
        int lvl = (int)lf - 2;           // 0..4 -> feat index
        if (tid == 0) s_lvl = lvl;

        float scale = 1.0f / (float)(4 << lvl);   // 2^-(lvl+2), exact
        int   HW    = 128 >> lvl;

        float x1 = rx1 * scale, y1 = ry1 * scale;
        float x2 = rx2 * scale, y2 = ry2 * scale;
        float rw = fmaxf(x2 - x1, 1.0f);
        float rh = fmaxf(y2 - y1, 1.0f);
        float bw = rw / (float)OUT;
        float bh = rh / (float)OUT;

        bool isx = (tid >= 14);
        int  g   = isx ? tid - 14 : tid;
        float gv = ((float)g + 0.5f) * 0.5f;          // oy + (iy+0.5)/2
        float p  = isx ? (x1 + gv * bw) : (y1 + gv * bh);

        int v = (p >= -1.0f && p <= (float)HW) ? 1 : 0;
        float pc  = fminf(fmaxf(p, 0.0f), (float)(HW - 1));
        float p0f = floorf(pc);
        int   p0  = (int)p0f;
        int   p1  = min(p0 + 1, HW - 1);
        float l   = pc - p0f;

        if (isx) { s_x0[g] = p0; s_x1[g] = p1; s_lx[g] = l; s_xv[g] = v; }
        else     { s_y0[g] = p0; s_y1[g] = p1; s_ly[g] = l; s_yv[g] = v; }
    }
    __syncthreads();

    const int lvl = s_lvl;
    const int HW  = 128 >> lvl;
    const float* f = (lvl == 0) ? f0 : (lvl == 1) ? f1 : (lvl == 2) ? f2
                     : (lvl == 3) ? f3 : f4;

    const int e  = blockIdx.x * 256 + tid;   // 0..12543
    const int c  = e / 49;
    const int s  = e - 49 * c;
    const int oy = s / 7;
    const int ox = s - 7 * oy;
    const int b  = roi >> 8;                 // roi / NN

    const float* fp = f + ((size_t)(b * NC + c)) * (size_t)(HW * HW);

    float acc = 0.0f;
    #pragma unroll
    for (int iy = 0; iy < 2; ++iy) {
        const int gy = oy * 2 + iy;
        if (!s_yv[gy]) continue;
        const float ly = s_ly[gy];
        const float* r0 = fp + s_y0[gy] * HW;
        const float* r1 = fp + s_y1[gy] * HW;
        #pragma unroll
        for (int ix = 0; ix < 2; ++ix) {
            const int gx = ox * 2 + ix;
            if (!s_xv[gx]) continue;
            const float lx = s_lx[gx];
            const int x0 = s_x0[gx], x1i = s_x1[gx];
            const float v00 = r0[x0], v01 = r0[x1i];
            const float v10 = r1[x0], v11 = r1[x1i];
            const float top = v00 + lx * (v01 - v00);
            const float bot = v10 + lx * (v11 - v10);
            acc += top + ly * (bot - top);
        }
    }

    out[(size_t)roi * ELEMS_PER_ROI + e] = acc * 0.25f;
}

extern "C" void kernel_launch(void* const* d_in, const int* in_sizes, int n_in,
                              void* d_out, int out_size, void* d_ws, size_t ws_size,
                              hipStream_t stream) {
    const float* f0   = (const float*)d_in[0];
    const float* f1   = (const float*)d_in[1];
    const float* f2   = (const float*)d_in[2];
    const float* f3   = (const float*)d_in[3];
    const float* f4   = (const float*)d_in[4];
    const float* rois = (const float*)d_in[5];
    float* out = (float*)d_out;

    dim3 grid(ELEMS_PER_ROI / 256, NB * NN);   // (49, 1024)
    dim3 block(256);
    msroi_kernel<<<grid, block, 0, stream>>>(f0, f1, f2, f3, f4, rois, out);
}

// Round 2
// 256.583 us; speedup vs baseline: 1.0304x; 1.0304x over previous
//
#include <hip/hip_runtime.h>

#define OUT 7
#define NB 4        // batch
#define NC 256      // channels
#define NN 256      // rois per image
#define EPR (NC * OUT * OUT)   // 12544 elements per roi

__global__ __launch_bounds__(256) void msroi_kernel(
    const float* __restrict__ f0, const float* __restrict__ f1,
    const float* __restrict__ f2, const float* __restrict__ f3,
    const float* __restrict__ f4, const float* __restrict__ rois,
    float* __restrict__ out)
{
    const int roi = blockIdx.y;
    const int tid = threadIdx.x;

    // Per-axis precomputed sampling data, valid flag folded into weights.
    __shared__ float s_wyt[14], s_wyb[14];   // vy*(1-ly), vy*ly
    __shared__ float s_wxl[14], s_wxr[14];   // vx*(1-lx), vx*lx
    __shared__ int   s_oy0[14], s_oy1[14];   // y0*HW, y1*HW
    __shared__ int   s_x0[14],  s_x1[14];
    __shared__ int   s_lvl;

    if (tid < 28) {
        const float rx1 = rois[roi * 4 + 0];
        const float ry1 = rois[roi * 4 + 1];
        const float rx2 = rois[roi * 4 + 2];
        const float ry2 = rois[roi * 4 + 3];

        float area = (rx2 - rx1) * (ry2 - ry1);
        float lf = floorf(4.0f + log2f(sqrtf(area) / 224.0f + 1e-6f));
        lf = fminf(fmaxf(lf, 2.0f), 6.0f);
        int lvl = (int)lf - 2;           // 0..4 -> feat index
        if (tid == 0) s_lvl = lvl;

        float scale = 1.0f / (float)(4 << lvl);   // exact 2^-(lvl+2)
        int   HW    = 128 >> lvl;

        float x1 = rx1 * scale, y1 = ry1 * scale;
        float x2 = rx2 * scale, y2 = ry2 * scale;
        float rw = fmaxf(x2 - x1, 1.0f);
        float rh = fmaxf(y2 - y1, 1.0f);
        float bw = rw / (float)OUT;
        float bh = rh / (float)OUT;

        bool isx = (tid >= 14);
        int  g   = isx ? tid - 14 : tid;
        float gv = ((float)g + 0.5f) * 0.5f;          // oy + (iy+0.5)/2
        float p  = isx ? (x1 + gv * bw) : (y1 + gv * bh);

        float v = (p >= -1.0f && p <= (float)HW) ? 1.0f : 0.0f;
        float pc  = fminf(fmaxf(p, 0.0f), (float)(HW - 1));
        float p0f = floorf(pc);
        int   p0  = (int)p0f;
        int   p1  = min(p0 + 1, HW - 1);
        float l   = pc - p0f;

        if (isx) {
            s_x0[g] = p0; s_x1[g] = p1;
            s_wxl[g] = v * (1.0f - l); s_wxr[g] = v * l;
        } else {
            s_oy0[g] = p0 * HW; s_oy1[g] = p1 * HW;
            s_wyt[g] = v * (1.0f - l); s_wyb[g] = v * l;
        }
    }
    __syncthreads();

    const int lvl = s_lvl;
    const int HW  = 128 >> lvl;
    const int HW2 = HW * HW;
    const float* f = (lvl == 0) ? f0 : (lvl == 1) ? f1 : (lvl == 2) ? f2
                     : (lvl == 3) ? f3 : f4;
    const int b = roi >> 8;                 // roi / NN

    const int e0 = blockIdx.x * 512 + tid;  // 2 outputs per thread

    float acc[2];
    #pragma unroll
    for (int k = 0; k < 2; ++k) {
        const int e  = e0 + k * 256;
        const int ec = (e < EPR) ? e : 0;   // tail guard (last block only)
        const int c  = ec / 49;
        const int s  = ec - 49 * c;
        const int oy = s / 7;
        const int ox = s - 7 * oy;

        const float* fp = f + (size_t)(b * NC + c) * (size_t)HW2;

        float a = 0.0f;
        #pragma unroll
        for (int iy = 0; iy < 2; ++iy) {
            const int gy = oy * 2 + iy;
            const float wt = s_wyt[gy], wb = s_wyb[gy];
            const int   o0 = s_oy0[gy], o1 = s_oy1[gy];
            #pragma unroll
            for (int ix = 0; ix < 2; ++ix) {
                const int gx = ox * 2 + ix;
                const float wl = s_wxl[gx], wr = s_wxr[gx];
                const int   x0 = s_x0[gx],  x1i = s_x1[gx];
                const float v00 = fp[o0 + x0];
                const float v01 = fp[o0 + x1i];
                const float v10 = fp[o1 + x0];
                const float v11 = fp[o1 + x1i];
                a += (wt * wl) * v00 + (wt * wr) * v01
                   + (wb * wl) * v10 + (wb * wr) * v11;
            }
        }
        acc[k] = a * 0.25f;
    }

    #pragma unroll
    for (int k = 0; k < 2; ++k) {
        const int e = e0 + k * 256;
        if (e < EPR)
            __builtin_nontemporal_store(acc[k], &out[(size_t)roi * EPR + e]);
    }
}

extern "C" void kernel_launch(void* const* d_in, const int* in_sizes, int n_in,
                              void* d_out, int out_size, void* d_ws, size_t ws_size,
                              hipStream_t stream) {
    const float* f0   = (const float*)d_in[0];
    const float* f1   = (const float*)d_in[1];
    const float* f2   = (const float*)d_in[2];
    const float* f3   = (const float*)d_in[3];
    const float* f4   = (const float*)d_in[4];
    const float* rois = (const float*)d_in[5];
    float* out = (float*)d_out;

    dim3 grid((EPR + 511) / 512, NB * NN);   // (25, 1024)
    dim3 block(256);
    msroi_kernel<<<grid, block, 0, stream>>>(f0, f1, f2, f3, f4, rois, out);
}

// Round 4
// 200.301 us; speedup vs baseline: 1.3199x; 1.2810x over previous
//
#include <hip/hip_runtime.h>

#define OUT 7
#define NB 4        // batch
#define NC 256      // channels
#define NN 256      // rois per image
#define EPR (NC * OUT * OUT)   // 12544 elements per roi

typedef float nfloat4 __attribute__((ext_vector_type(4)));

// ---------------------------------------------------------------------------
// Kernel 1: transpose one FPN level [B][C][P] -> [B][P][C]   (P = H*W)
// grid (P/32, C/32, B), block (8,32). 32x32 tile, +1 pad, float4 global I/O.
// ---------------------------------------------------------------------------
__global__ __launch_bounds__(256) void transpose_cl(
    const float* __restrict__ in, float* __restrict__ outT, int P)
{
    __shared__ float tile[32][33];
    const int p0 = blockIdx.x * 32;
    const int c0 = blockIdx.y * 32;
    const int b  = blockIdx.z;
    const int tx = threadIdx.x;   // 0..7
    const int ty = threadIdx.y;   // 0..31

    const float* src = in + ((size_t)(b * NC + c0 + ty)) * P + p0 + tx * 4;
    nfloat4 v = *(const nfloat4*)src;
    tile[ty][tx * 4 + 0] = v.x;
    tile[ty][tx * 4 + 1] = v.y;
    tile[ty][tx * 4 + 2] = v.z;
    tile[ty][tx * 4 + 3] = v.w;
    __syncthreads();

    nfloat4 w;
    w.x = tile[4 * tx + 0][ty];
    w.y = tile[4 * tx + 1][ty];
    w.z = tile[4 * tx + 2][ty];
    w.w = tile[4 * tx + 3][ty];
    float* dst = outT + ((size_t)b * P + p0 + ty) * NC + c0 + tx * 4;
    *(nfloat4*)dst = w;
}

// ---------------------------------------------------------------------------
// Kernel 2: one block per roi, thread = channel. All 16 corner gathers are
// wave-coalesced (64 consecutive channels). Output staged in LDS (flat roi
// layout), then stored as coalesced nontemporal float4.
// ---------------------------------------------------------------------------
__global__ __launch_bounds__(256) void msroi_fast(
    const float* __restrict__ T, const float* __restrict__ rois,
    float* __restrict__ out)
{
    const int roi = blockIdx.x;
    const int c   = threadIdx.x;

    __shared__ float s_wyt[14], s_wyb[14], s_wxl[14], s_wxr[14];
    __shared__ int   s_yr0[14], s_yr1[14], s_x0[14], s_x1[14];
    __shared__ int   s_lvl;
    __shared__ __align__(16) float s_out[EPR];   // 50176 B

    if (c < 28) {
        const float rx1 = rois[roi * 4 + 0];
        const float ry1 = rois[roi * 4 + 1];
        const float rx2 = rois[roi * 4 + 2];
        const float ry2 = rois[roi * 4 + 3];

        float area = (rx2 - rx1) * (ry2 - ry1);
        float lf = floorf(4.0f + log2f(sqrtf(area) / 224.0f + 1e-6f));
        lf = fminf(fmaxf(lf, 2.0f), 6.0f);
        int lvl = (int)lf - 2;
        if (c == 0) s_lvl = lvl;

        float scale = 1.0f / (float)(4 << lvl);
        int   W     = 128 >> lvl;

        float x1 = rx1 * scale, y1 = ry1 * scale;
        float x2 = rx2 * scale, y2 = ry2 * scale;
        float rw = fmaxf(x2 - x1, 1.0f);
        float rh = fmaxf(y2 - y1, 1.0f);
        float bw = rw / (float)OUT;
        float bh = rh / (float)OUT;

        bool isx = (c >= 14);
        int  g   = isx ? c - 14 : c;
        float gv = ((float)g + 0.5f) * 0.5f;
        float p  = isx ? (x1 + gv * bw) : (y1 + gv * bh);

        float v = (p >= -1.0f && p <= (float)W) ? 1.0f : 0.0f;
        float pc  = fminf(fmaxf(p, 0.0f), (float)(W - 1));
        float p0f = floorf(pc);
        int   p0  = (int)p0f;
        int   p1  = min(p0 + 1, W - 1);
        float l   = pc - p0f;

        if (isx) {
            s_x0[g] = p0; s_x1[g] = p1;
            s_wxl[g] = v * (1.0f - l); s_wxr[g] = v * l;
        } else {
            s_yr0[g] = p0 * W; s_yr1[g] = p1 * W;
            s_wyt[g] = v * (1.0f - l); s_wyb[g] = v * l;
        }
    }
    __syncthreads();

    const int lvl = s_lvl;
    const int W   = 128 >> lvl;
    const int POS = W * W;
    const int off_tab[5] = {0, 16777216, 20971520, 22020096, 22282240};
    const int b = roi >> 8;
    const float* base = T + (size_t)off_tab[lvl] + (size_t)b * POS * NC + c;

    for (int oy = 0; oy < OUT; ++oy) {
        const int gy0 = oy * 2, gy1 = gy0 + 1;
        const float wt0 = s_wyt[gy0], wb0 = s_wyb[gy0];
        const float wt1 = s_wyt[gy1], wb1 = s_wyb[gy1];
        const int r00 = s_yr0[gy0], r01 = s_yr1[gy0];
        const int r10 = s_yr0[gy1], r11 = s_yr1[gy1];
        #pragma unroll
        for (int ox = 0; ox < OUT; ++ox) {
            const int gx0 = ox * 2, gx1 = gx0 + 1;
            const float wl0 = s_wxl[gx0], wr0 = s_wxr[gx0];
            const float wl1 = s_wxl[gx1], wr1 = s_wxr[gx1];
            const int x00 = s_x0[gx0], x01 = s_x1[gx0];
            const int x10 = s_x0[gx1], x11 = s_x1[gx1];

            float acc;
            acc  = wt0 * (wl0 * base[(r00 + x00) << 8] + wr0 * base[(r00 + x01) << 8])
                 + wb0 * (wl0 * base[(r01 + x00) << 8] + wr0 * base[(r01 + x01) << 8]);
            acc += wt0 * (wl1 * base[(r00 + x10) << 8] + wr1 * base[(r00 + x11) << 8])
                 + wb0 * (wl1 * base[(r01 + x10) << 8] + wr1 * base[(r01 + x11) << 8]);
            acc += wt1 * (wl0 * base[(r10 + x00) << 8] + wr0 * base[(r10 + x01) << 8])
                 + wb1 * (wl0 * base[(r11 + x00) << 8] + wr0 * base[(r11 + x01) << 8]);
            acc += wt1 * (wl1 * base[(r10 + x10) << 8] + wr1 * base[(r10 + x11) << 8])
                 + wb1 * (wl1 * base[(r11 + x10) << 8] + wr1 * base[(r11 + x11) << 8]);

            s_out[c * 49 + oy * 7 + ox] = acc * 0.25f;   // stride 49: conflict-free
        }
    }
    __syncthreads();

    // cooperative coalesced store of the flat 12544-float roi block
    float* ob = out + (size_t)roi * EPR;
    #pragma unroll
    for (int k = 0; k < 12; ++k) {
        const int f = (c + (k << 8)) << 2;
        nfloat4 v = *(const nfloat4*)&s_out[f];
        __builtin_nontemporal_store(v, (nfloat4*)&ob[f]);
    }
    if (c < 64) {
        const int f = (c + 3072) << 2;
        nfloat4 v = *(const nfloat4*)&s_out[f];
        __builtin_nontemporal_store(v, (nfloat4*)&ob[f]);
    }
}

// ---------------------------------------------------------------------------
// Fallback (round-2 kernel) if workspace is too small for the transposed copy
// ---------------------------------------------------------------------------
__global__ __launch_bounds__(256) void msroi_kernel(
    const float* __restrict__ f0, const float* __restrict__ f1,
    const float* __restrict__ f2, const float* __restrict__ f3,
    const float* __restrict__ f4, const float* __restrict__ rois,
    float* __restrict__ out)
{
    const int roi = blockIdx.y;
    const int tid = threadIdx.x;

    __shared__ float s_wyt[14], s_wyb[14];
    __shared__ float s_wxl[14], s_wxr[14];
    __shared__ int   s_oy0[14], s_oy1[14];
    __shared__ int   s_x0[14],  s_x1[14];
    __shared__ int   s_lvl;

    if (tid < 28) {
        const float rx1 = rois[roi * 4 + 0];
        const float ry1 = rois[roi * 4 + 1];
        const float rx2 = rois[roi * 4 + 2];
        const float ry2 = rois[roi * 4 + 3];

        float area = (rx2 - rx1) * (ry2 - ry1);
        float lf = floorf(4.0f + log2f(sqrtf(area) / 224.0f + 1e-6f));
        lf = fminf(fmaxf(lf, 2.0f), 6.0f);
        int lvl = (int)lf - 2;
        if (tid == 0) s_lvl = lvl;

        float scale = 1.0f / (float)(4 << lvl);
        int   HW    = 128 >> lvl;

        float x1 = rx1 * scale, y1 = ry1 * scale;
        float x2 = rx2 * scale, y2 = ry2 * scale;
        float rw = fmaxf(x2 - x1, 1.0f);
        float rh = fmaxf(y2 - y1, 1.0f);
        float bw = rw / (float)OUT;
        float bh = rh / (float)OUT;

        bool isx = (tid >= 14);
        int  g   = isx ? tid - 14 : tid;
        float gv = ((float)g + 0.5f) * 0.5f;
        float p  = isx ? (x1 + gv * bw) : (y1 + gv * bh);

        float v = (p >= -1.0f && p <= (float)HW) ? 1.0f : 0.0f;
        float pc  = fminf(fmaxf(p, 0.0f), (float)(HW - 1));
        float p0f = floorf(pc);
        int   p0  = (int)p0f;
        int   p1  = min(p0 + 1, HW - 1);
        float l   = pc - p0f;

        if (isx) {
            s_x0[g] = p0; s_x1[g] = p1;
            s_wxl[g] = v * (1.0f - l); s_wxr[g] = v * l;
        } else {
            s_oy0[g] = p0 * HW; s_oy1[g] = p1 * HW;
            s_wyt[g] = v * (1.0f - l); s_wyb[g] = v * l;
        }
    }
    __syncthreads();

    const int lvl = s_lvl;
    const int HW  = 128 >> lvl;
    const int HW2 = HW * HW;
    const float* f = (lvl == 0) ? f0 : (lvl == 1) ? f1 : (lvl == 2) ? f2
                     : (lvl == 3) ? f3 : f4;
    const int b = roi >> 8;

    const int e0 = blockIdx.x * 512 + tid;

    float acc[2];
    #pragma unroll
    for (int k = 0; k < 2; ++k) {
        const int e  = e0 + k * 256;
        const int ec = (e < EPR) ? e : 0;
        const int c  = ec / 49;
        const int s  = ec - 49 * c;
        const int oy = s / 7;
        const int ox = s - 7 * oy;

        const float* fp = f + (size_t)(b * NC + c) * (size_t)HW2;

        float a = 0.0f;
        #pragma unroll
        for (int iy = 0; iy < 2; ++iy) {
            const int gy = oy * 2 + iy;
            const float wt = s_wyt[gy], wb = s_wyb[gy];
            const int   o0 = s_oy0[gy], o1 = s_oy1[gy];
            #pragma unroll
            for (int ix = 0; ix < 2; ++ix) {
                const int gx = ox * 2 + ix;
                const float wl = s_wxl[gx], wr = s_wxr[gx];
                const int   x0 = s_x0[gx],  x1i = s_x1[gx];
                const float v00 = fp[o0 + x0];
                const float v01 = fp[o0 + x1i];
                const float v10 = fp[o1 + x0];
                const float v11 = fp[o1 + x1i];
                a += (wt * wl) * v00 + (wt * wr) * v01
                   + (wb * wl) * v10 + (wb * wr) * v11;
            }
        }
        acc[k] = a * 0.25f;
    }

    #pragma unroll
    for (int k = 0; k < 2; ++k) {
        const int e = e0 + k * 256;
        if (e < EPR)
            __builtin_nontemporal_store(acc[k], &out[(size_t)roi * EPR + e]);
    }
}

extern "C" void kernel_launch(void* const* d_in, const int* in_sizes, int n_in,
                              void* d_out, int out_size, void* d_ws, size_t ws_size,
                              hipStream_t stream) {
    const float* f[5] = {(const float*)d_in[0], (const float*)d_in[1],
                         (const float*)d_in[2], (const float*)d_in[3],
                         (const float*)d_in[4]};
    const float* rois = (const float*)d_in[5];
    float* out = (float*)d_out;

    const size_t need = 22347776ull * 4ull;   // 89.4 MB transposed features
    if (ws_size >= need) {
        float* T = (float*)d_ws;
        const int P[5]   = {16384, 4096, 1024, 256, 64};
        const int off[5] = {0, 16777216, 20971520, 22020096, 22282240};
        for (int l = 0; l < 5; ++l) {
            dim3 g(P[l] / 32, NC / 32, NB);
            dim3 blk(8, 32);
            transpose_cl<<<g, blk, 0, stream>>>(f[l], T + off[l], P[l]);
        }
        msroi_fast<<<dim3(NB * NN), dim3(256), 0, stream>>>(T, rois, out);
    } else {
        dim3 grid((EPR + 511) / 512, NB * NN);
        dim3 block(256);
        msroi_kernel<<<grid, block, 0, stream>>>(f[0], f[1], f[2], f[3], f[4],
                                                 rois, out);
    }
}